// Round 1
// baseline (2774.222 us; speedup 1.0000x reference)
//
#include <hip/hip_runtime.h>
#include <math.h>

#define NU 100000
#define NI 50000
#define NT 150000      // NU + NI
#define D  64
#define NNZ_ 4000000
#define BATCH_ 4096
#define WDECAY 1e-4f

// ---------------- init: cur = acc = concat(user_emb, item_emb); zero scalars --
__global__ void init_kernel(const float* __restrict__ ue, const float* __restrict__ ie,
                            float* __restrict__ cur, float* __restrict__ acc,
                            float* __restrict__ scal) {
    int i = blockIdx.x * blockDim.x + threadIdx.x;
    const int total = NT * D;            // 9.6M < 2^31
    if (i == 0) { scal[0] = 0.f; scal[1] = 0.f; }
    const int stride = gridDim.x * blockDim.x;
    const int usz = NU * D;
    for (; i < total; i += stride) {
        float v = (i < usz) ? ue[i] : ie[i - usz];
        cur[i] = v;
        acc[i] = v;
    }
}

// ---------------- SpMM: y += A x  (y pre-zeroed). One wave per nnz. ----------
__global__ void spmm_kernel(const int* __restrict__ rows, const int* __restrict__ cols,
                            const float* __restrict__ vals,
                            const float* __restrict__ x, float* __restrict__ y) {
    int gtid = blockIdx.x * blockDim.x + threadIdx.x;
    int wid  = gtid >> 6;
    int lane = threadIdx.x & 63;
    int nw   = (gridDim.x * blockDim.x) >> 6;
    for (int e = wid; e < NNZ_; e += nw) {
        int   r = rows[e];
        int   c = cols[e];
        float v = vals[e];
        float xv = x[c * D + lane];
        atomicAdd(&y[r * D + lane], v * xv);
    }
}

// ---------------- acc += nxt -------------------------------------------------
__global__ void axpy_kernel(float* __restrict__ acc, const float* __restrict__ nxt) {
    int i = blockIdx.x * blockDim.x + threadIdx.x;
    const int total = NT * D;
    const int stride = gridDim.x * blockDim.x;
    for (; i < total; i += stride)
        acc[i] += nxt[i];
}

// ---------------- per-batch loss partials: one wave per batch element --------
__global__ void loss_kernel(const float* __restrict__ acc,
                            const float* __restrict__ ue, const float* __restrict__ ie,
                            const int* __restrict__ users, const int* __restrict__ pos,
                            const int* __restrict__ neg, float* __restrict__ scal) {
    int gtid = blockIdx.x * blockDim.x + threadIdx.x;
    int wid  = gtid >> 6;
    int lane = threadIdx.x & 63;
    int nw   = (gridDim.x * blockDim.x) >> 6;
    for (int b = wid; b < BATCH_; b += nw) {
        int u = users[b], p = pos[b], n = neg[b];
        float ueL = acc[u * D + lane];
        float peL = acc[(NU + p) * D + lane];
        float neL = acc[(NU + n) * D + lane];
        float uo = ue[u * D + lane];
        float po = ie[p * D + lane];
        float no = ie[n * D + lane];
        float ps = ueL * peL;
        float ns = ueL * neL;
        float rg = uo * uo + po * po + no * no;
        #pragma unroll
        for (int off = 32; off > 0; off >>= 1) {
            ps += __shfl_down(ps, off);
            ns += __shfl_down(ns, off);
            rg += __shfl_down(rg, off);
        }
        if (lane == 0) {
            // light_out = acc/4  ->  dot products scale by 1/16
            float diff = (ns - ps) * (1.0f / 16.0f);
            float sp = diff > 0.f ? diff + log1pf(expf(-diff)) : log1pf(expf(diff));
            atomicAdd(&scal[0], sp);
            atomicAdd(&scal[1], rg);
        }
    }
}

// ---------------- finalize ---------------------------------------------------
__global__ void finalize_kernel(const float* __restrict__ scal, float* __restrict__ out) {
    out[0] = scal[0] / (float)BATCH_ + WDECAY * 0.5f * scal[1] / (float)BATCH_;
}

extern "C" void kernel_launch(void* const* d_in, const int* in_sizes, int n_in,
                              void* d_out, int out_size, void* d_ws, size_t ws_size,
                              hipStream_t stream) {
    const float* user_emb = (const float*)d_in[0];
    const float* item_emb = (const float*)d_in[1];
    const int*   g_rows   = (const int*)d_in[2];
    const int*   g_cols   = (const int*)d_in[3];
    const float* g_vals   = (const float*)d_in[4];
    const int*   users    = (const int*)d_in[5];
    const int*   pos      = (const int*)d_in[6];
    const int*   neg      = (const int*)d_in[7];
    float* out = (float*)d_out;

    const size_t TAB_BYTES = (size_t)NT * D * sizeof(float);   // 38.4 MB
    char* ws = (char*)d_ws;
    float* cur  = (float*)(ws);
    float* nxt  = (float*)(ws + TAB_BYTES);
    float* acc  = (float*)(ws + 2 * TAB_BYTES);
    float* scal = (float*)(ws + 3 * TAB_BYTES);

    init_kernel<<<2048, 256, 0, stream>>>(user_emb, item_emb, cur, acc, scal);

    for (int layer = 0; layer < 3; ++layer) {
        hipMemsetAsync(nxt, 0, TAB_BYTES, stream);
        spmm_kernel<<<2048, 256, 0, stream>>>(g_rows, g_cols, g_vals, cur, nxt);
        axpy_kernel<<<2048, 256, 0, stream>>>(acc, nxt);
        float* t = cur; cur = nxt; nxt = t;
    }

    loss_kernel<<<1024, 256, 0, stream>>>(acc, user_emb, item_emb, users, pos, neg, scal);
    finalize_kernel<<<1, 1, 0, stream>>>(scal, out);
}

// Round 2
// 1325.901 us; speedup vs baseline: 2.0923x; 2.0923x over previous
//
#include <hip/hip_runtime.h>
#include <math.h>

#define NU 100000
#define NI 50000
#define NT 150000      // NU + NI
#define D  64
#define NNZ_ 4000000
#define BATCH_ 4096
#define WDECAY 1e-4f
#define NB_SCAN ((NT + 255) / 256)   // 586

// ---------------- init: cur = acc = concat(user_emb, item_emb); zero scalars --
__global__ void init_kernel(const float* __restrict__ ue, const float* __restrict__ ie,
                            float* __restrict__ cur, float* __restrict__ acc,
                            float* __restrict__ scal) {
    int i = blockIdx.x * blockDim.x + threadIdx.x;
    const int total = NT * D;
    if (i == 0) { scal[0] = 0.f; scal[1] = 0.f; }
    const int stride = gridDim.x * blockDim.x;
    const int usz = NU * D;
    for (; i < total; i += stride) {
        float v = (i < usz) ? ue[i] : ie[i - usz];
        cur[i] = v;
        acc[i] = v;
    }
}

// ---------------- CSR build step 1: histogram of rows ------------------------
__global__ void hist_kernel(const int* __restrict__ rows, int* __restrict__ cnt) {
    int i = blockIdx.x * blockDim.x + threadIdx.x;
    int stride = gridDim.x * blockDim.x;
    for (; i < NNZ_; i += stride)
        atomicAdd(&cnt[rows[i]], 1);
}

// ---------------- CSR step 2a: per-256-block exclusive scan ------------------
__global__ void scan1_kernel(const int* __restrict__ cnt, int* __restrict__ rowptr,
                             int* __restrict__ bsum) {
    __shared__ int s[256];
    int tid = threadIdx.x;
    int i = blockIdx.x * 256 + tid;
    int v = (i < NT) ? cnt[i] : 0;
    s[tid] = v; __syncthreads();
    for (int off = 1; off < 256; off <<= 1) {
        int t = (tid >= off) ? s[tid - off] : 0;
        __syncthreads();
        s[tid] += t;
        __syncthreads();
    }
    int incl = s[tid];
    if (i < NT) rowptr[i] = incl - v;          // exclusive
    if (tid == 255) bsum[blockIdx.x] = incl;   // block total
}

// ---------------- CSR step 2b: scan of block sums (single block) -------------
__global__ void scan2_kernel(int* __restrict__ bsum, int* __restrict__ rowptr) {
    __shared__ int s[1024];
    int t = threadIdx.x;
    int v = (t < NB_SCAN) ? bsum[t] : 0;
    s[t] = v; __syncthreads();
    for (int off = 1; off < 1024; off <<= 1) {
        int x = (t >= off) ? s[t - off] : 0;
        __syncthreads();
        s[t] += x;
        __syncthreads();
    }
    if (t < NB_SCAN) bsum[t] = s[t] - v;       // exclusive block offsets
    if (t == 0) rowptr[NT] = NNZ_;
}

// ---------------- CSR step 2c: add block offsets, init write cursors ---------
__global__ void scan3_kernel(int* __restrict__ rowptr, const int* __restrict__ bsum,
                             int* __restrict__ woff) {
    int i = blockIdx.x * blockDim.x + threadIdx.x;
    int stride = gridDim.x * blockDim.x;
    for (; i < NT; i += stride) {
        int r = rowptr[i] + bsum[i >> 8];
        rowptr[i] = r;
        woff[i] = r;
    }
}

// ---------------- CSR step 3: scatter (col,val) into row buckets -------------
__global__ void scatter_kernel(const int* __restrict__ rows, const int* __restrict__ cols,
                               const float* __restrict__ vals,
                               int* __restrict__ woff, int2* __restrict__ colval) {
    int i = blockIdx.x * blockDim.x + threadIdx.x;
    int stride = gridDim.x * blockDim.x;
    for (; i < NNZ_; i += stride) {
        int r = rows[i];
        int p = atomicAdd(&woff[r], 1);
        int2 cv; cv.x = cols[i]; cv.y = __float_as_int(vals[i]);
        colval[p] = cv;
    }
}

// ---------------- SpMM (CSR, gather): one wave per row; fused acc += --------
template<int WRITE_NXT>
__global__ void spmm_csr_kernel(const int* __restrict__ rowptr,
                                const int2* __restrict__ colval,
                                const float* __restrict__ x,
                                float* __restrict__ nxt, float* __restrict__ acc) {
    int gtid = blockIdx.x * blockDim.x + threadIdx.x;
    int r    = gtid >> 6;          // one wave per row
    int lane = threadIdx.x & 63;
    if (r >= NT) return;
    int beg = rowptr[r], end = rowptr[r + 1];
    float s = 0.f;
    for (int base = beg; base < end; base += 64) {
        int m = end - base; if (m > 64) m = 64;
        int idx = base + lane; if (idx > NNZ_ - 1) idx = NNZ_ - 1;
        int2 cv = colval[idx];
        for (int j = 0; j < m; ++j) {
            int   c = __shfl(cv.x, j);
            float v = __int_as_float(__shfl(cv.y, j));
            s += v * x[c * D + lane];
        }
    }
    int o = r * D + lane;
    if (WRITE_NXT) nxt[o] = s;
    acc[o] += s;
}

// ---------------- per-batch loss partials: one wave per batch element --------
__global__ void loss_kernel(const float* __restrict__ acc,
                            const float* __restrict__ ue, const float* __restrict__ ie,
                            const int* __restrict__ users, const int* __restrict__ pos,
                            const int* __restrict__ neg, float* __restrict__ scal) {
    int gtid = blockIdx.x * blockDim.x + threadIdx.x;
    int wid  = gtid >> 6;
    int lane = threadIdx.x & 63;
    int nw   = (gridDim.x * blockDim.x) >> 6;
    for (int b = wid; b < BATCH_; b += nw) {
        int u = users[b], p = pos[b], n = neg[b];
        float ueL = acc[u * D + lane];
        float peL = acc[(NU + p) * D + lane];
        float neL = acc[(NU + n) * D + lane];
        float uo = ue[u * D + lane];
        float po = ie[p * D + lane];
        float no = ie[n * D + lane];
        float ps = ueL * peL;
        float ns = ueL * neL;
        float rg = uo * uo + po * po + no * no;
        #pragma unroll
        for (int off = 32; off > 0; off >>= 1) {
            ps += __shfl_down(ps, off);
            ns += __shfl_down(ns, off);
            rg += __shfl_down(rg, off);
        }
        if (lane == 0) {
            float diff = (ns - ps) * (1.0f / 16.0f);   // light_out = acc/4
            float sp = diff > 0.f ? diff + log1pf(expf(-diff)) : log1pf(expf(diff));
            atomicAdd(&scal[0], sp);
            atomicAdd(&scal[1], rg);
        }
    }
}

// ---------------- finalize ---------------------------------------------------
__global__ void finalize_kernel(const float* __restrict__ scal, float* __restrict__ out) {
    out[0] = scal[0] / (float)BATCH_ + WDECAY * 0.5f * scal[1] / (float)BATCH_;
}

extern "C" void kernel_launch(void* const* d_in, const int* in_sizes, int n_in,
                              void* d_out, int out_size, void* d_ws, size_t ws_size,
                              hipStream_t stream) {
    const float* user_emb = (const float*)d_in[0];
    const float* item_emb = (const float*)d_in[1];
    const int*   g_rows   = (const int*)d_in[2];
    const int*   g_cols   = (const int*)d_in[3];
    const float* g_vals   = (const float*)d_in[4];
    const int*   users    = (const int*)d_in[5];
    const int*   pos      = (const int*)d_in[6];
    const int*   neg      = (const int*)d_in[7];
    float* out = (float*)d_out;

    const size_t TAB = (size_t)NT * D * sizeof(float);     // 38,400,000 B
    char* ws = (char*)d_ws;
    float* cur    = (float*)(ws);
    float* nxt    = (float*)(ws + TAB);
    float* acc    = (float*)(ws + 2 * TAB);
    int2*  colval = (int2*) (ws + 3 * TAB);                // 32,000,000 B
    char*  p      = ws + 3 * TAB + (size_t)NNZ_ * 8;
    int*   rowptr = (int*)(p);            p += ((size_t)(NT + 1) * 4 + 255) / 256 * 256;
    int*   woff   = (int*)(p);            p += ((size_t)NT * 4 + 255) / 256 * 256;
    int*   cnt    = (int*)(p);            p += ((size_t)NT * 4 + 255) / 256 * 256;
    int*   bsum   = (int*)(p);            p += 4096;
    float* scal   = (float*)(p);

    // CSR build
    hipMemsetAsync(cnt, 0, (size_t)NT * 4, stream);
    init_kernel<<<2048, 256, 0, stream>>>(user_emb, item_emb, cur, acc, scal);
    hist_kernel<<<2048, 256, 0, stream>>>(g_rows, cnt);
    scan1_kernel<<<NB_SCAN, 256, 0, stream>>>(cnt, rowptr, bsum);
    scan2_kernel<<<1, 1024, 0, stream>>>(bsum, rowptr);
    scan3_kernel<<<512, 256, 0, stream>>>(rowptr, bsum, woff);
    scatter_kernel<<<2048, 256, 0, stream>>>(g_rows, g_cols, g_vals, woff, colval);

    // 3 propagation layers, acc += fused; last layer skips nxt write
    const int SPMM_BLOCKS = (NT + 3) / 4;   // one wave per row, 4 waves/block
    spmm_csr_kernel<1><<<SPMM_BLOCKS, 256, 0, stream>>>(rowptr, colval, cur, nxt, acc);
    spmm_csr_kernel<1><<<SPMM_BLOCKS, 256, 0, stream>>>(rowptr, colval, nxt, cur, acc);
    spmm_csr_kernel<0><<<SPMM_BLOCKS, 256, 0, stream>>>(rowptr, colval, cur, nxt, acc);

    loss_kernel<<<1024, 256, 0, stream>>>(acc, user_emb, item_emb, users, pos, neg, scal);
    finalize_kernel<<<1, 1, 0, stream>>>(scal, out);
}

// Round 3
// 981.661 us; speedup vs baseline: 2.8260x; 1.3507x over previous
//
#include <hip/hip_runtime.h>
#include <hip/hip_bf16.h>
#include <math.h>

#define NU 100000
#define NI 50000
#define NT 150000      // NU + NI
#define D  64
#define NNZ_ 4000000
#define BATCH_ 4096
#define WDECAY 1e-4f

#define NBKT 293        // ceil(150000/512) buckets of 512 rows
#define BCAP 16384      // bucket capacity (mean 13653, sigma ~117 -> 23 sigma pad)
#define CURS 16         // cursor stride in ints (64B padding vs atomic contention)

static __device__ __forceinline__ float bf2f(ushort u) {
    unsigned int x = ((unsigned int)u) << 16;
    return __uint_as_float(x);
}
static __device__ __forceinline__ ushort f2bf(float f) {
    unsigned int u = __float_as_uint(f);
    u += 0x7FFF + ((u >> 16) & 1);      // round-to-nearest-even
    return (ushort)(u >> 16);
}

// ---- init: cur0 = bf16(concat(ue, ie)); zero loss scalars -------------------
__global__ void init_kernel(const float* __restrict__ ue, const float* __restrict__ ie,
                            ushort* __restrict__ cur0, float* __restrict__ scal) {
    int i = blockIdx.x * blockDim.x + threadIdx.x;   // one float4 per thread
    const int total4 = NT * D / 4;
    if (i == 0) { scal[0] = 0.f; scal[1] = 0.f; }
    if (i >= total4) return;
    const int usz4 = NU * D / 4;
    float4 v = (i < usz4) ? ((const float4*)ue)[i] : ((const float4*)ie)[i - usz4];
    ushort4 o;
    o.x = f2bf(v.x); o.y = f2bf(v.y); o.z = f2bf(v.z); o.w = f2bf(v.w);
    ((ushort4*)cur0)[i] = o;
}

// ---- pass A: append edges into row-range buckets ----------------------------
__global__ void binA_kernel(const int* __restrict__ rows, const int* __restrict__ cols,
                            const float* __restrict__ vals,
                            int* __restrict__ cursor, int2* __restrict__ binned) {
    int i = blockIdx.x * blockDim.x + threadIdx.x;
    int stride = gridDim.x * blockDim.x;
    for (; i < NNZ_; i += stride) {
        int r = rows[i];
        int b = r >> 9;
        int p = atomicAdd(&cursor[b * CURS], 1);
        int2 e;
        e.x = (r & 511) | (cols[i] << 9);
        e.y = __float_as_int(vals[i]);
        binned[b * BCAP + p] = e;
    }
}

// ---- bucket-base scan (single block) ----------------------------------------
__global__ void bscan_kernel(const int* __restrict__ cursor, int* __restrict__ bbase,
                             int* __restrict__ rowptr) {
    __shared__ int s[512];
    int t = threadIdx.x;
    int v = (t < NBKT) ? cursor[t * CURS] : 0;
    s[t] = v; __syncthreads();
    for (int off = 1; off < 512; off <<= 1) {
        int x = (t >= off) ? s[t - off] : 0;
        __syncthreads();
        s[t] += x;
        __syncthreads();
    }
    if (t < NBKT) bbase[t] = s[t] - v;    // exclusive
    if (t == 0) rowptr[NT] = NNZ_;
}

// ---- pass B: per-bucket LDS counting sort -> CSR ----------------------------
__global__ void binB_kernel(const int2* __restrict__ binned, const int* __restrict__ cursor,
                            const int* __restrict__ bbase,
                            int2* __restrict__ colval, int* __restrict__ rowptr) {
    __shared__ int cnt[512];
    __shared__ int offs[512];
    int b   = blockIdx.x;
    int tid = threadIdx.x;
    int cb  = cursor[b * CURS];
    int base = bbase[b];
    const int2* eb = binned + (size_t)b * BCAP;
    if (tid < 512) cnt[tid] = 0;
    __syncthreads();
    for (int i = tid; i < cb; i += 1024)
        atomicAdd(&cnt[eb[i].x & 511], 1);
    __syncthreads();
    int v = (tid < 512) ? cnt[tid] : 0;
    for (int off = 1; off < 512; off <<= 1) {
        int x = (tid < 512 && tid >= off) ? cnt[tid - off] : 0;
        __syncthreads();
        if (tid < 512) cnt[tid] += x;
        __syncthreads();
    }
    if (tid < 512) {
        int excl = cnt[tid] - v;
        offs[tid] = excl;
        int row = b * 512 + tid;
        if (row < NT) rowptr[row] = base + excl;
    }
    __syncthreads();
    for (int i = tid; i < cb; i += 1024) {
        int2 e = eb[i];
        int rl = e.x & 511;
        int p  = base + atomicAdd(&offs[rl], 1);
        int2 cv; cv.x = e.x >> 9; cv.y = e.y;
        colval[p] = cv;
    }
}

// ---- SpMM (CSR gather, bf16 in/out): one wave per row -----------------------
__global__ void spmm_kernel(const int* __restrict__ rowptr, const int2* __restrict__ colval,
                            const ushort* __restrict__ x, ushort* __restrict__ y) {
    int gtid = blockIdx.x * blockDim.x + threadIdx.x;
    int r    = gtid >> 6;
    int lane = threadIdx.x & 63;
    if (r >= NT) return;
    int beg = rowptr[r], end = rowptr[r + 1];
    float s = 0.f;
    for (int base = beg; base < end; base += 64) {
        int m = end - base; if (m > 64) m = 64;
        int idx = base + lane; if (idx > NNZ_ - 1) idx = NNZ_ - 1;
        int2 cv = colval[idx];
        for (int j = 0; j < m; ++j) {
            int   c = __shfl(cv.x, j);
            float v = __int_as_float(__shfl(cv.y, j));
            s += v * bf2f(x[c * D + lane]);
        }
    }
    y[r * D + lane] = f2bf(s);
}

// ---- row walk: one SpMM row on the fly (layer 3), per-lane dim value --------
static __device__ __forceinline__ float row_walk(const int* __restrict__ rowptr,
                                                 const int2* __restrict__ colval,
                                                 const ushort* __restrict__ x,
                                                 int r, int lane) {
    int beg = rowptr[r], end = rowptr[r + 1];
    float s = 0.f;
    for (int base = beg; base < end; base += 64) {
        int m = end - base; if (m > 64) m = 64;
        int idx = base + lane; if (idx > NNZ_ - 1) idx = NNZ_ - 1;
        int2 cv = colval[idx];
        for (int j = 0; j < m; ++j) {
            int   c = __shfl(cv.x, j);
            float v = __int_as_float(__shfl(cv.y, j));
            s += v * bf2f(x[c * D + lane]);
        }
    }
    return s;
}

// ---- loss: light = (e0 + o1 + o2 + walk(o2))/4, fused layer 3 ---------------
__global__ void loss_kernel(const float* __restrict__ ue, const float* __restrict__ ie,
                            const ushort* __restrict__ o1, const ushort* __restrict__ o2,
                            const int* __restrict__ rowptr, const int2* __restrict__ colval,
                            const int* __restrict__ users, const int* __restrict__ pos,
                            const int* __restrict__ neg, float* __restrict__ scal) {
    int gtid = blockIdx.x * blockDim.x + threadIdx.x;
    int wid  = gtid >> 6;
    int lane = threadIdx.x & 63;
    int nw   = (gridDim.x * blockDim.x) >> 6;
    for (int b = wid; b < BATCH_; b += nw) {
        int u = users[b], p = pos[b], n = neg[b];
        int ru = u, rp = NU + p, rn = NU + n;
        float uo = ue[u * D + lane];
        float po = ie[p * D + lane];
        float no = ie[n * D + lane];
        float lu = uo + bf2f(o1[ru * D + lane]) + bf2f(o2[ru * D + lane])
                      + row_walk(rowptr, colval, o2, ru, lane);
        float lp = po + bf2f(o1[rp * D + lane]) + bf2f(o2[rp * D + lane])
                      + row_walk(rowptr, colval, o2, rp, lane);
        float ln_ = no + bf2f(o1[rn * D + lane]) + bf2f(o2[rn * D + lane])
                      + row_walk(rowptr, colval, o2, rn, lane);
        float ps = lu * lp;
        float ns = lu * ln_;
        float rg = uo * uo + po * po + no * no;
        #pragma unroll
        for (int off = 32; off > 0; off >>= 1) {
            ps += __shfl_down(ps, off);
            ns += __shfl_down(ns, off);
            rg += __shfl_down(rg, off);
        }
        if (lane == 0) {
            float diff = (ns - ps) * (1.0f / 16.0f);   // (acc/4) dots
            float sp = diff > 0.f ? diff + log1pf(expf(-diff)) : log1pf(expf(diff));
            atomicAdd(&scal[0], sp);
            atomicAdd(&scal[1], rg);
        }
    }
}

__global__ void finalize_kernel(const float* __restrict__ scal, float* __restrict__ out) {
    out[0] = scal[0] / (float)BATCH_ + WDECAY * 0.5f * scal[1] / (float)BATCH_;
}

extern "C" void kernel_launch(void* const* d_in, const int* in_sizes, int n_in,
                              void* d_out, int out_size, void* d_ws, size_t ws_size,
                              hipStream_t stream) {
    const float* user_emb = (const float*)d_in[0];
    const float* item_emb = (const float*)d_in[1];
    const int*   g_rows   = (const int*)d_in[2];
    const int*   g_cols   = (const int*)d_in[3];
    const float* g_vals   = (const float*)d_in[4];
    const int*   users    = (const int*)d_in[5];
    const int*   pos      = (const int*)d_in[6];
    const int*   neg      = (const int*)d_in[7];
    float* out = (float*)d_out;

    const size_t TABH = (size_t)NT * D * 2;            // 19.2 MB bf16 table
    char* ws = (char*)d_ws;
    ushort* cur0  = (ushort*)(ws);
    ushort* o1    = (ushort*)(ws + TABH);
    ushort* o2    = (ushort*)(ws + 2 * TABH);
    int2*   colval= (int2*)  (ws + 3 * TABH);                       // 32 MB
    int2*   binned= (int2*)  (ws + 3 * TABH + (size_t)NNZ_ * 8);    // 38.4 MB
    char*   p     = ws + 3 * TABH + (size_t)NNZ_ * 8 + (size_t)NBKT * BCAP * 8;
    int*    rowptr= (int*)(p);      p += ((size_t)(NT + 1) * 4 + 255) / 256 * 256;
    int*    cursor= (int*)(p);      p += (size_t)NBKT * CURS * 4;
    int*    bbase = (int*)(p);      p += 2048;
    float*  scal  = (float*)(p);

    hipMemsetAsync(cursor, 0, (size_t)NBKT * CURS * 4, stream);
    init_kernel<<<(NT * D / 4 + 255) / 256, 256, 0, stream>>>(user_emb, item_emb, cur0, scal);

    binA_kernel<<<2048, 256, 0, stream>>>(g_rows, g_cols, g_vals, cursor, binned);
    bscan_kernel<<<1, 512, 0, stream>>>(cursor, bbase, rowptr);
    binB_kernel<<<NBKT, 1024, 0, stream>>>(binned, cursor, bbase, colval, rowptr);

    const int SPMM_BLOCKS = (NT + 3) / 4;   // one wave per row, 4 waves/block
    spmm_kernel<<<SPMM_BLOCKS, 256, 0, stream>>>(rowptr, colval, cur0, o1);
    spmm_kernel<<<SPMM_BLOCKS, 256, 0, stream>>>(rowptr, colval, o1, o2);

    loss_kernel<<<1024, 256, 0, stream>>>(user_emb, item_emb, o1, o2, rowptr, colval,
                                          users, pos, neg, scal);
    finalize_kernel<<<1, 1, 0, stream>>>(scal, out);
}

// Round 4
// 567.425 us; speedup vs baseline: 4.8891x; 1.7300x over previous
//
#include <hip/hip_runtime.h>
#include <math.h>

#define NU 100000
#define NI 50000
#define NT 150000      // NU + NI
#define D  64
#define NNZ_ 4000000
#define BATCH_ 4096
#define WDECAY 1e-4f

#define BROWS 2048                 // rows per bucket
#define NBKT 74                    // ceil(NT / BROWS)
#define BCAP 57344                 // bucket capacity (mean 54613, sigma ~234)
#define CURS 16                    // cursor stride (64B anti-contention pad)
#define EPB 16                     // edges per thread in binA
#define BATCH_E (256 * EPB)        // 4096 edges per block-batch
#define NBLK_A ((NNZ_ + BATCH_E - 1) / BATCH_E)   // 977

static __device__ __forceinline__ float bf2f(ushort u) {
    return __uint_as_float(((unsigned int)u) << 16);
}
static __device__ __forceinline__ ushort f2bf(float f) {
    unsigned int u = __float_as_uint(f);
    u += 0x7FFF + ((u >> 16) & 1);      // RTNE
    return (ushort)(u >> 16);
}

// ---- init: cur0 = bf16(concat(ue, ie)); zero loss scalars -------------------
__global__ void init_kernel(const float* __restrict__ ue, const float* __restrict__ ie,
                            ushort* __restrict__ cur0, float* __restrict__ scal) {
    int i = blockIdx.x * blockDim.x + threadIdx.x;
    const int total4 = NT * D / 4;
    if (i == 0) { scal[0] = 0.f; scal[1] = 0.f; }
    if (i >= total4) return;
    const int usz4 = NU * D / 4;
    float4 v = (i < usz4) ? ((const float4*)ue)[i] : ((const float4*)ie)[i - usz4];
    ushort4 o;
    o.x = f2bf(v.x); o.y = f2bf(v.y); o.z = f2bf(v.z); o.w = f2bf(v.w);
    ((ushort4*)cur0)[i] = o;
}

// ---- binA: block-aggregated bucket append (runs are block-private) ----------
__global__ void binA_kernel(const int* __restrict__ rows, const int* __restrict__ cols,
                            const float* __restrict__ vals,
                            int* __restrict__ cursor, int2* __restrict__ binned) {
    __shared__ int cnt[NBKT];
    __shared__ int gbase[NBKT];
    int tid = threadIdx.x;
    int b0 = blockIdx.x * BATCH_E;
    if (tid < NBKT) cnt[tid] = 0;
    __syncthreads();
    // phase 1: rank within (batch, bucket).  pack = rl | (bkt<<11) | (rank<<18)
    int pack[EPB];
    #pragma unroll
    for (int k = 0; k < EPB; ++k) {
        int i = b0 + k * 256 + tid;
        if (i < NNZ_) {
            int r = rows[i];
            int b = r >> 11;
            int rk = atomicAdd(&cnt[b], 1);
            pack[k] = (r & (BROWS - 1)) | (b << 11) | (rk << 18);
        } else pack[k] = -1;
    }
    __syncthreads();
    // phase 2: reserve one contiguous global run per bucket
    if (tid < NBKT) {
        int c = cnt[tid];
        gbase[tid] = c ? atomicAdd(&cursor[tid * CURS], c) : 0;
    }
    __syncthreads();
    // phase 3: write (cols/vals read here; L2-hot rows range not re-needed)
    #pragma unroll
    for (int k = 0; k < EPB; ++k) {
        int pk = pack[k];
        if (pk >= 0) {
            int i  = b0 + k * 256 + tid;
            int rl = pk & (BROWS - 1);
            int b  = (pk >> 11) & 127;
            int rk = pk >> 18;
            int2 e;
            e.x = rl | (cols[i] << 11);
            e.y = __float_as_int(vals[i]);
            binned[(size_t)b * BCAP + gbase[b] + rk] = e;
        }
    }
}

// ---- bucket-base scan (74 buckets, single block) ----------------------------
__global__ void bscan_kernel(const int* __restrict__ cursor, int* __restrict__ bbase,
                             int* __restrict__ rowptr) {
    __shared__ int s[128];
    int t = threadIdx.x;
    int v = (t < NBKT) ? cursor[t * CURS] : 0;
    s[t] = v; __syncthreads();
    for (int off = 1; off < 128; off <<= 1) {
        int x = (t >= off) ? s[t - off] : 0;
        __syncthreads();
        s[t] += x;
        __syncthreads();
    }
    if (t < NBKT) bbase[t] = s[t] - v;
    if (t == 0) rowptr[NT] = NNZ_;
}

// ---- binB: per-bucket LDS counting sort (2048 rows) -> CSR ------------------
__global__ void binB_kernel(const int2* __restrict__ binned, const int* __restrict__ cursor,
                            const int* __restrict__ bbase,
                            int2* __restrict__ colval, int* __restrict__ rowptr) {
    __shared__ int cnt[BROWS];
    __shared__ int sc[1024];
    __shared__ int offs[BROWS];
    int b   = blockIdx.x;
    int tid = threadIdx.x;
    int cb  = cursor[b * CURS];
    int base = bbase[b];
    const int2* eb = binned + (size_t)b * BCAP;
    cnt[tid] = 0; cnt[tid + 1024] = 0;
    __syncthreads();
    for (int i = tid; i < cb; i += 1024)
        atomicAdd(&cnt[eb[i].x & (BROWS - 1)], 1);
    __syncthreads();
    // scan 2048 via pair-compress + Hillis-Steele(1024)
    int v0 = cnt[2 * tid], v1 = cnt[2 * tid + 1];
    sc[tid] = v0 + v1;
    __syncthreads();
    for (int off = 1; off < 1024; off <<= 1) {
        int x = (tid >= off) ? sc[tid - off] : 0;
        __syncthreads();
        sc[tid] += x;
        __syncthreads();
    }
    int pbase = sc[tid] - (v0 + v1);           // exclusive pair base
    offs[2 * tid]     = pbase;
    offs[2 * tid + 1] = pbase + v0;
    int row0 = b * BROWS + 2 * tid;
    if (row0 < NT)     rowptr[row0]     = base + pbase;
    if (row0 + 1 < NT) rowptr[row0 + 1] = base + pbase + v0;
    __syncthreads();
    for (int i = tid; i < cb; i += 1024) {
        int2 e = eb[i];
        int rl = e.x & (BROWS - 1);
        int p  = base + atomicAdd(&offs[rl], 1);
        int2 cv; cv.x = e.x >> 11; cv.y = e.y;
        colval[p] = cv;
    }
}

// ---- quad-ILP row core: 4 edges in flight, ushort4 gathers ------------------
// returns s0..s3 (dims 4*ql .. 4*ql+3), already reduced across quarters
static __device__ __forceinline__ void row_core(const int* __restrict__ rowptr,
                                                const int2* __restrict__ colval,
                                                const ushort* __restrict__ x,
                                                int r, int lane,
                                                float& s0, float& s1, float& s2, float& s3) {
    int q  = lane >> 4;
    int ql = lane & 15;
    int beg = rowptr[r], end = rowptr[r + 1];
    s0 = s1 = s2 = s3 = 0.f;
    for (int base = beg; base < end; base += 64) {
        int m = end - base; if (m > 64) m = 64;
        int idx = base + lane; if (idx > NNZ_ - 1) idx = NNZ_ - 1;
        int2 cv = colval[idx];
        int nq = (m + 3) >> 2;
        #pragma unroll 4
        for (int j = 0; j < nq; ++j) {
            int e = 4 * j + q;
            int   c = __shfl(cv.x, e);
            float v = __int_as_float(__shfl(cv.y, e));
            if (e >= m) v = 0.f;
            ushort4 xv = *(const ushort4*)(x + (size_t)c * D + ql * 4);
            s0 += v * bf2f(xv.x); s1 += v * bf2f(xv.y);
            s2 += v * bf2f(xv.z); s3 += v * bf2f(xv.w);
        }
    }
    s0 += __shfl_xor(s0, 16); s0 += __shfl_xor(s0, 32);
    s1 += __shfl_xor(s1, 16); s1 += __shfl_xor(s1, 32);
    s2 += __shfl_xor(s2, 16); s2 += __shfl_xor(s2, 32);
    s3 += __shfl_xor(s3, 16); s3 += __shfl_xor(s3, 32);
}

// ---- SpMM (CSR gather): one wave per row ------------------------------------
__global__ void spmm_kernel(const int* __restrict__ rowptr, const int2* __restrict__ colval,
                            const ushort* __restrict__ x, ushort* __restrict__ y) {
    int gtid = blockIdx.x * blockDim.x + threadIdx.x;
    int r    = gtid >> 6;
    int lane = threadIdx.x & 63;
    if (r >= NT) return;
    float s0, s1, s2, s3;
    row_core(rowptr, colval, x, r, lane, s0, s1, s2, s3);
    if ((lane >> 4) == 0) {
        int ql = lane & 15;
        ushort4 o;
        o.x = f2bf(s0); o.y = f2bf(s1); o.z = f2bf(s2); o.w = f2bf(s3);
        *(ushort4*)(y + (size_t)r * D + ql * 4) = o;
    }
}

// ---- row walk for fused layer 3: value for dim = lane -----------------------
static __device__ __forceinline__ float row_walk(const int* __restrict__ rowptr,
                                                 const int2* __restrict__ colval,
                                                 const ushort* __restrict__ x,
                                                 int r, int lane) {
    float s0, s1, s2, s3;
    row_core(rowptr, colval, x, r, lane, s0, s1, s2, s3);
    int srcl = lane >> 2;
    float w0 = __shfl(s0, srcl), w1 = __shfl(s1, srcl);
    float w2 = __shfl(s2, srcl), w3 = __shfl(s3, srcl);
    int sel = lane & 3;
    return sel == 0 ? w0 : sel == 1 ? w1 : sel == 2 ? w2 : w3;
}

// ---- loss: light = (e0 + o1 + o2 + walk(o2))/4, fused layer 3 ---------------
__global__ void loss_kernel(const float* __restrict__ ue, const float* __restrict__ ie,
                            const ushort* __restrict__ o1, const ushort* __restrict__ o2,
                            const int* __restrict__ rowptr, const int2* __restrict__ colval,
                            const int* __restrict__ users, const int* __restrict__ pos,
                            const int* __restrict__ neg, float* __restrict__ scal) {
    int gtid = blockIdx.x * blockDim.x + threadIdx.x;
    int wid  = gtid >> 6;
    int lane = threadIdx.x & 63;
    int nw   = (gridDim.x * blockDim.x) >> 6;
    for (int b = wid; b < BATCH_; b += nw) {
        int u = users[b], p = pos[b], n = neg[b];
        int ru = u, rp = NU + p, rn = NU + n;
        float uo = ue[(size_t)u * D + lane];
        float po = ie[(size_t)p * D + lane];
        float no = ie[(size_t)n * D + lane];
        float lu = uo + bf2f(o1[(size_t)ru * D + lane]) + bf2f(o2[(size_t)ru * D + lane])
                      + row_walk(rowptr, colval, o2, ru, lane);
        float lp = po + bf2f(o1[(size_t)rp * D + lane]) + bf2f(o2[(size_t)rp * D + lane])
                      + row_walk(rowptr, colval, o2, rp, lane);
        float ln_ = no + bf2f(o1[(size_t)rn * D + lane]) + bf2f(o2[(size_t)rn * D + lane])
                      + row_walk(rowptr, colval, o2, rn, lane);
        float ps = lu * lp;
        float ns = lu * ln_;
        float rg = uo * uo + po * po + no * no;
        #pragma unroll
        for (int off = 32; off > 0; off >>= 1) {
            ps += __shfl_down(ps, off);
            ns += __shfl_down(ns, off);
            rg += __shfl_down(rg, off);
        }
        if (lane == 0) {
            float diff = (ns - ps) * (1.0f / 16.0f);
            float sp = diff > 0.f ? diff + log1pf(expf(-diff)) : log1pf(expf(diff));
            atomicAdd(&scal[0], sp);
            atomicAdd(&scal[1], rg);
        }
    }
}

__global__ void finalize_kernel(const float* __restrict__ scal, float* __restrict__ out) {
    out[0] = scal[0] / (float)BATCH_ + WDECAY * 0.5f * scal[1] / (float)BATCH_;
}

extern "C" void kernel_launch(void* const* d_in, const int* in_sizes, int n_in,
                              void* d_out, int out_size, void* d_ws, size_t ws_size,
                              hipStream_t stream) {
    const float* user_emb = (const float*)d_in[0];
    const float* item_emb = (const float*)d_in[1];
    const int*   g_rows   = (const int*)d_in[2];
    const int*   g_cols   = (const int*)d_in[3];
    const float* g_vals   = (const float*)d_in[4];
    const int*   users    = (const int*)d_in[5];
    const int*   pos      = (const int*)d_in[6];
    const int*   neg      = (const int*)d_in[7];
    float* out = (float*)d_out;

    const size_t TABH = (size_t)NT * D * 2;            // 19.2 MB bf16 table
    char* ws = (char*)d_ws;
    ushort* cur0   = (ushort*)(ws);
    ushort* o1     = (ushort*)(ws + TABH);
    ushort* o2     = (ushort*)(ws + 2 * TABH);
    int2*   colval = (int2*)  (ws + 3 * TABH);                       // 32 MB
    int2*   binned = (int2*)  (ws + 3 * TABH + (size_t)NNZ_ * 8);    // 33.9 MB
    char*   p      = ws + 3 * TABH + (size_t)NNZ_ * 8 + (size_t)NBKT * BCAP * 8;
    int*    rowptr = (int*)(p);      p += ((size_t)(NT + 1) * 4 + 255) / 256 * 256;
    int*    cursor = (int*)(p);      p += (size_t)NBKT * CURS * 4;
    int*    bbase  = (int*)(p);      p += 1024;
    float*  scal   = (float*)(p);

    hipMemsetAsync(cursor, 0, (size_t)NBKT * CURS * 4, stream);
    init_kernel<<<(NT * D / 4 + 255) / 256, 256, 0, stream>>>(user_emb, item_emb, cur0, scal);

    binA_kernel<<<NBLK_A, 256, 0, stream>>>(g_rows, g_cols, g_vals, cursor, binned);
    bscan_kernel<<<1, 128, 0, stream>>>(cursor, bbase, rowptr);
    binB_kernel<<<NBKT, 1024, 0, stream>>>(binned, cursor, bbase, colval, rowptr);

    const int SPMM_BLOCKS = (NT + 3) / 4;   // one wave per row, 4 waves/block
    spmm_kernel<<<SPMM_BLOCKS, 256, 0, stream>>>(rowptr, colval, cur0, o1);
    spmm_kernel<<<SPMM_BLOCKS, 256, 0, stream>>>(rowptr, colval, o1, o2);

    loss_kernel<<<1024, 256, 0, stream>>>(user_emb, item_emb, o1, o2, rowptr, colval,
                                          users, pos, neg, scal);
    finalize_kernel<<<1, 1, 0, stream>>>(scal, out);
}